// Round 1
// baseline (887.846 us; speedup 1.0000x reference)
//
#include <hip/hip_runtime.h>

#define N_   32
#define CIN  64
#define COUT 128
#define T_   300
#define V_   25
#define K_   3
#define EPS  1e-5f
#define M_TOT 240000.0f   // N*T*V

// ws layout (floats):
//   [0, 24576)           WgT[kc][o]  (kc = k*64+c, o = 0..127)
//   [24576, 32768)       WrT[c][o]
//   [32768, 33280)       stats: sH[128] sH2[128] sR[128] sR2[128]
//   [33280, 33664)       coefs: scaleH[128] scaleR[128] biasC[128]
#define WS_WGT   0
#define WS_WRT   24576
#define WS_STATS 32768
#define WS_COEF  33280

__global__ void prep_kernel(const float* __restrict__ Wg,
                            const float* __restrict__ Wr,
                            float* __restrict__ ws) {
    int i = blockIdx.x * blockDim.x + threadIdx.x;
    const int tot = 24576 + 8192 + 512;
    for (; i < tot; i += gridDim.x * blockDim.x) {
        if (i < 24576) {
            int kc = i >> 7, o = i & 127;
            int k = kc >> 6, c = kc & 63;
            ws[WS_WGT + i] = Wg[(k * COUT + o) * CIN + c];
        } else if (i < 24576 + 8192) {
            int j = i - 24576;
            int c = j >> 7, o = j & 127;
            ws[WS_WRT + j] = Wr[o * CIN + c];
        } else {
            ws[WS_STATS + (i - (24576 + 8192))] = 0.0f;
        }
    }
}

__global__ void finalize_kernel(const float* __restrict__ g1, const float* __restrict__ b1,
                                const float* __restrict__ g2, const float* __restrict__ b2,
                                float* __restrict__ ws) {
    int o = threadIdx.x;  // 128 threads
    const float inv_m = 1.0f / M_TOT;
    float meanH = ws[WS_STATS + o] * inv_m;
    float varH  = ws[WS_STATS + 128 + o] * inv_m - meanH * meanH;
    float invH  = rsqrtf(varH + EPS);
    float meanR = ws[WS_STATS + 256 + o] * inv_m;
    float varR  = ws[WS_STATS + 384 + o] * inv_m - meanR * meanR;
    float invR  = rsqrtf(varR + EPS);
    float scH = g1[o] * invH;
    float scR = g2[o] * invR;
    ws[WS_COEF + o]       = scH;
    ws[WS_COEF + 128 + o] = scR;
    ws[WS_COEF + 256 + o] = b1[o] + b2[o] - scH * meanH - scR * meanR;
}

// One block per (n, t). 128 threads; thread tid owns output channel o = tid.
template <bool WRITE>
__global__ __launch_bounds__(128) void pass_kernel(
    const float* __restrict__ x, const float* __restrict__ A,
    const float* __restrict__ ga, const float* __restrict__ bg,
    const float* __restrict__ br, float* __restrict__ ws,
    float* __restrict__ out) {
    __shared__ __align__(16) float xs[CIN * 28];        // x[c][v], row stride 28
    __shared__ __align__(16) float aes[K_ * V_ * V_];   // Ae[k][v][w]
    __shared__ __align__(16) float xas[K_ * CIN * 28];  // xa[kc][w], row stride 28

    const int nt = blockIdx.x;
    const int n = nt / T_;
    const int t = nt % T_;
    const int tid = threadIdx.x;

    // Stage Ae = A * graph_attn
    for (int e = tid; e < K_ * V_ * V_; e += 128) aes[e] = A[e] * ga[e];
    // Stage x[n, :, t, :]
    for (int e = tid; e < CIN * V_; e += 128) {
        int c = e / V_, v = e % V_;
        xs[c * 28 + v] = x[((n * CIN + c) * T_ + t) * V_ + v];
    }
    __syncthreads();

    // xa[kc][w] = sum_v x[c][v] * Ae[k][v][w]
    for (int e = tid; e < K_ * CIN * V_; e += 128) {
        int kc = e / V_, w = e % V_;
        int k = kc >> 6, c = kc & 63;
        const float* xr = &xs[c * 28];
        const float* ar = &aes[k * 625 + w];
        float acc = 0.0f;
#pragma unroll
        for (int v = 0; v < V_; ++v) acc += xr[v] * ar[v * 25];
        xas[kc * 28 + w] = acc;
    }
    __syncthreads();

    const int o = tid;
    float accH[25], accR[25];
    const float hb = bg[o] + bg[COUT + o] + bg[2 * COUT + o];
#pragma unroll
    for (int w = 0; w < 25; ++w) accH[w] = hb;

    // hidden[o][w] = hb + sum_kc WgT[kc][o] * xa[kc][w]
    const float* wgt = &ws[WS_WGT + o];
    for (int kc = 0; kc < K_ * CIN; ++kc) {
        float wg = wgt[kc * 128];
        const float* xr = &xas[kc * 28];
#pragma unroll
        for (int q = 0; q < 6; ++q) {
            float4 a = *reinterpret_cast<const float4*>(xr + 4 * q);
            accH[4 * q + 0] += wg * a.x;
            accH[4 * q + 1] += wg * a.y;
            accH[4 * q + 2] += wg * a.z;
            accH[4 * q + 3] += wg * a.w;
        }
        accH[24] += wg * xr[24];
    }

    // res[o][v] = br[o] + sum_c WrT[c][o] * x[c][v]
    const float rb = br[o];
#pragma unroll
    for (int w = 0; w < 25; ++w) accR[w] = rb;
    const float* wrt = &ws[WS_WRT + o];
    for (int c = 0; c < CIN; ++c) {
        float wr = wrt[c * 128];
        const float* xr = &xs[c * 28];
#pragma unroll
        for (int q = 0; q < 6; ++q) {
            float4 a = *reinterpret_cast<const float4*>(xr + 4 * q);
            accR[4 * q + 0] += wr * a.x;
            accR[4 * q + 1] += wr * a.y;
            accR[4 * q + 2] += wr * a.z;
            accR[4 * q + 3] += wr * a.w;
        }
        accR[24] += wr * xr[24];
    }

    if (!WRITE) {
        float sH = 0, sH2 = 0, sR = 0, sR2 = 0;
#pragma unroll
        for (int w = 0; w < 25; ++w) {
            sH += accH[w];
            sH2 += accH[w] * accH[w];
            sR += accR[w];
            sR2 += accR[w] * accR[w];
        }
        atomicAdd(&ws[WS_STATS + o], sH);
        atomicAdd(&ws[WS_STATS + 128 + o], sH2);
        atomicAdd(&ws[WS_STATS + 256 + o], sR);
        atomicAdd(&ws[WS_STATS + 384 + o], sR2);
    } else {
        const float scH = ws[WS_COEF + o];
        const float scR = ws[WS_COEF + 128 + o];
        const float bC  = ws[WS_COEF + 256 + o];
        float* op = &out[((size_t)(n * COUT + o) * T_ + t) * V_];
#pragma unroll
        for (int w = 0; w < 25; ++w) op[w] = scH * accH[w] + scR * accR[w] + bC;
    }
}

extern "C" void kernel_launch(void* const* d_in, const int* in_sizes, int n_in,
                              void* d_out, int out_size, void* d_ws, size_t ws_size,
                              hipStream_t stream) {
    const float* x        = (const float*)d_in[0];
    const float* A        = (const float*)d_in[1];
    const float* ga       = (const float*)d_in[2];
    const float* Wg       = (const float*)d_in[3];
    const float* bg       = (const float*)d_in[4];
    const float* bn_gamma = (const float*)d_in[5];
    const float* bn_beta  = (const float*)d_in[6];
    const float* Wr       = (const float*)d_in[7];
    const float* br       = (const float*)d_in[8];
    const float* rbn_g    = (const float*)d_in[9];
    const float* rbn_b    = (const float*)d_in[10];
    float* ws  = (float*)d_ws;
    float* out = (float*)d_out;

    prep_kernel<<<64, 256, 0, stream>>>(Wg, Wr, ws);
    pass_kernel<false><<<N_ * T_, 128, 0, stream>>>(x, A, ga, bg, br, ws, nullptr);
    finalize_kernel<<<1, 128, 0, stream>>>(bn_gamma, bn_beta, rbn_g, rbn_b, ws);
    pass_kernel<true><<<N_ * T_, 128, 0, stream>>>(x, A, ga, bg, br, ws, out);
}

// Round 2
// 271.350 us; speedup vs baseline: 3.2720x; 3.2720x over previous
//
#include <hip/hip_runtime.h>

typedef __attribute__((ext_vector_type(8))) short short8;
typedef __attribute__((ext_vector_type(4))) float float4v;

#define N_   32
#define CIN  64
#define COUT 128
#define T_   300
#define V_   25
#define K_   3
#define EPS  1e-5f
#define M_TOT 240000.0f   // N*T*V

// ws BYTE offsets
#define WS_WFRAG  0        // ushort [8 mt][8 kt][64 lane][8 j]   = 65536 B
#define WS_AEFRAG 65536    // ushort [3 k][2 nt][64 lane][8 j]    = 6144 B
#define WS_STATS  71680    // float[512]: sH,sH2,sR,sR2 x 128
#define WS_COEF   73728    // float[384]: scH, scR, bC x 128

__device__ __forceinline__ unsigned short f2bf(float f) {
    unsigned u = __builtin_bit_cast(unsigned, f);
    u += 0x7FFFu + ((u >> 16) & 1u);
    return (unsigned short)(u >> 16);
}

__global__ void prep_kernel(const float* __restrict__ A, const float* __restrict__ ga,
                            const float* __restrict__ Wg, const float* __restrict__ Wr,
                            char* __restrict__ wsb) {
    unsigned short* wf = (unsigned short*)(wsb + WS_WFRAG);
    unsigned short* ae = (unsigned short*)(wsb + WS_AEFRAG);
    float* st = (float*)(wsb + WS_STATS);
    int i = blockIdx.x * blockDim.x + threadIdx.x;
    const int tot = 32768 + 3072 + 512;
    for (; i < tot; i += gridDim.x * blockDim.x) {
        if (i < 32768) {
            // A-operand fragments for stage2: o = mt*16+(l&15), kc = kt*32+(l>>4)*8+j
            int mt = i >> 12, kt = (i >> 9) & 7, l = (i >> 3) & 63, j = i & 7;
            int o = mt * 16 + (l & 15);
            int kc = kt * 32 + ((l >> 4) << 3) + j;
            float v;
            if (kc < 192) v = Wg[((kc >> 6) * COUT + o) * CIN + (kc & 63)];
            else          v = Wr[o * CIN + (kc - 192)];
            wf[i] = f2bf(v);
        } else if (i < 32768 + 3072) {
            // B-operand fragments for stage1: B[v][w] = Ae[k][v][w], v = (l>>4)*8+j, w = nt*16+(l&15)
            int q = i - 32768;
            int k = q >> 10, nt = (q >> 9) & 1, l = (q >> 3) & 63, j = q & 7;
            int v = ((l >> 4) << 3) + j;
            int w = nt * 16 + (l & 15);
            float val = (v < V_ && w < V_) ? A[(k * V_ + v) * V_ + w] * ga[(k * V_ + v) * V_ + w] : 0.0f;
            ae[q] = f2bf(val);
        } else {
            st[i - 32768 - 3072] = 0.0f;
        }
    }
}

__global__ void finalize_kernel(const float* __restrict__ g1, const float* __restrict__ b1,
                                const float* __restrict__ g2, const float* __restrict__ b2,
                                char* __restrict__ wsb) {
    float* st = (float*)(wsb + WS_STATS);
    float* cf = (float*)(wsb + WS_COEF);
    int o = threadIdx.x;  // 128
    const float inv_m = 1.0f / M_TOT;
    float meanH = st[o] * inv_m;
    float varH  = st[128 + o] * inv_m - meanH * meanH;
    float invH  = rsqrtf(varH + EPS);
    float meanR = st[256 + o] * inv_m;
    float varR  = st[384 + o] * inv_m - meanR * meanR;
    float invR  = rsqrtf(varR + EPS);
    float scH = g1[o] * invH;
    float scR = g2[o] * invR;
    cf[o]       = scH;
    cf[128 + o] = scR;
    cf[256 + o] = b1[o] + b2[o] - scH * meanH - scR * meanR;
}

// PASS 0: accumulate BN stats.  PASS 1: apply folded BN and write output.
// Block: 256 threads (4 waves). Tile: one n, 2 t's -> 64 padded columns (v 25->32).
// Wave wv owns o-slice [wv*32, wv*32+32), all 64 columns.
template <int PASS>
__global__ __launch_bounds__(256, 2) void gcn_kernel(
    const float* __restrict__ x, const float* __restrict__ bg, const float* __restrict__ br,
    char* __restrict__ wsb, float* __restrict__ out) {
    __shared__ unsigned short xa_lds[64][264];   // [col][kc] kc: 0..191 xa, 192..255 x ; 528B row
    __shared__ unsigned short xs[2][64][40];     // [t][c][v-pad], 80B row

    const unsigned short* wf = (const unsigned short*)(wsb + WS_WFRAG);
    const unsigned short* ae = (const unsigned short*)(wsb + WS_AEFRAG);
    float* st = (float*)(wsb + WS_STATS);
    const float* cf = (const float*)(wsb + WS_COEF);

    const int tid = threadIdx.x;
    const int wv = tid >> 6;
    const int l = tid & 63;
    const int l15 = l & 15, lq = l >> 4;

    // resident A-fragments (weights): o-tile = wv*2+mt
    short8 af[2][8];
#pragma unroll
    for (int mt = 0; mt < 2; ++mt)
#pragma unroll
        for (int kt = 0; kt < 8; ++kt)
            af[mt][kt] = *(const short8*)&wf[(((wv * 2 + mt) * 8 + kt) * 64 + l) * 8];

    // resident B-fragments for aggregation
    short8 aef[3][2];
#pragma unroll
    for (int k = 0; k < 3; ++k)
#pragma unroll
        for (int nt = 0; nt < 2; ++nt)
            aef[k][nt] = *(const short8*)&ae[((k * 2 + nt) * 64 + l) * 8];

    float hb[2][4], rb[2][4];
#pragma unroll
    for (int mt = 0; mt < 2; ++mt)
#pragma unroll
        for (int r = 0; r < 4; ++r) {
            int o = wv * 32 + mt * 16 + lq * 4 + r;
            hb[mt][r] = bg[o] + bg[COUT + o] + bg[2 * COUT + o];
            rb[mt][r] = br[o];
        }

    float scH[2][4], scR[2][4], bC[2][4];
    if (PASS == 1) {
#pragma unroll
        for (int mt = 0; mt < 2; ++mt)
#pragma unroll
            for (int r = 0; r < 4; ++r) {
                int o = wv * 32 + mt * 16 + lq * 4 + r;
                scH[mt][r] = cf[o];
                scR[mt][r] = cf[128 + o];
                bC[mt][r]  = cf[256 + o];
            }
    }

    float sH[8], sH2[8], sR[8], sR2[8];
    if (PASS == 0) {
#pragma unroll
        for (int i = 0; i < 8; ++i) { sH[i] = 0; sH2[i] = 0; sR[i] = 0; sR2[i] = 0; }
    }

    // zero LDS once (pads stay zero across tiles)
    for (int i = tid; i < 2 * 64 * 40; i += 256) ((unsigned short*)xs)[i] = 0;
    for (int i = tid; i < 64 * 264; i += 256) ((unsigned short*)xa_lds)[i] = 0;
    __syncthreads();

    for (int it = 0; it < 4; ++it) {
        const int tile = blockIdx.x * 4 + it;
        const int n = tile / 150;
        const int t0 = (tile % 150) * 2;

        // ---- stage x (fp32 -> bf16) into xs and residual rows of xa_lds ----
        for (int e = tid; e < 3200; e += 256) {
            int c = e / 50, rr = e % 50, tl = rr / 25, v = rr % 25;
            float xv = x[((n * CIN + c) * T_ + (t0 + tl)) * V_ + v];
            unsigned short b = f2bf(xv);
            xs[tl][c][v] = b;
            xa_lds[tl * 32 + v][192 + c] = b;
        }
        __syncthreads();

        // ---- stage1: XA[c,w] = sum_v X[c,v] * Ae[k][v,w] via MFMA; wave owns c-slice ----
#pragma unroll
        for (int t = 0; t < 2; ++t) {
            short8 xfrag = *(const short8*)&xs[t][wv * 16 + l15][lq * 8];
#pragma unroll
            for (int k = 0; k < 3; ++k) {
#pragma unroll
                for (int nt = 0; nt < 2; ++nt) {
                    float4v c4 = {0.0f, 0.0f, 0.0f, 0.0f};
                    c4 = __builtin_amdgcn_mfma_f32_16x16x32_bf16(xfrag, aef[k][nt], c4, 0, 0, 0);
                    int col = t * 32 + nt * 16 + l15;
                    int kc0 = k * 64 + wv * 16 + lq * 4;
                    unsigned long long p =
                        (unsigned long long)f2bf(c4[0]) |
                        ((unsigned long long)f2bf(c4[1]) << 16) |
                        ((unsigned long long)f2bf(c4[2]) << 32) |
                        ((unsigned long long)f2bf(c4[3]) << 48);
                    *(unsigned long long*)&xa_lds[col][kc0] = p;
                }
            }
        }
        __syncthreads();

        // ---- stage2: H = Wg . xa (kt 0..5), R = Wr . x (kt 6..7) ----
        float4v accH[2][4], accR[2][4];
#pragma unroll
        for (int mt = 0; mt < 2; ++mt)
#pragma unroll
            for (int nt = 0; nt < 4; ++nt) {
                float4v a, b;
#pragma unroll
                for (int r = 0; r < 4; ++r) { a[r] = hb[mt][r]; b[r] = rb[mt][r]; }
                accH[mt][nt] = a;
                accR[mt][nt] = b;
            }

#pragma unroll
        for (int kt = 0; kt < 8; ++kt) {
#pragma unroll
            for (int nt = 0; nt < 4; ++nt) {
                short8 bf = *(const short8*)&xa_lds[nt * 16 + l15][kt * 32 + lq * 8];
                if (kt < 6) {
#pragma unroll
                    for (int mt = 0; mt < 2; ++mt)
                        accH[mt][nt] = __builtin_amdgcn_mfma_f32_16x16x32_bf16(af[mt][kt], bf, accH[mt][nt], 0, 0, 0);
                } else {
#pragma unroll
                    for (int mt = 0; mt < 2; ++mt)
                        accR[mt][nt] = __builtin_amdgcn_mfma_f32_16x16x32_bf16(af[mt][kt], bf, accR[mt][nt], 0, 0, 0);
                }
            }
        }

        // ---- epilogue ----
        if (PASS == 0) {
#pragma unroll
            for (int mt = 0; mt < 2; ++mt)
#pragma unroll
                for (int nt = 0; nt < 4; ++nt) {
                    int col = nt * 16 + l15;
                    if ((col & 31) < V_) {
#pragma unroll
                        for (int r = 0; r < 4; ++r) {
                            float h = accH[mt][nt][r];
                            float rv = accR[mt][nt][r];
                            sH[mt * 4 + r]  += h;
                            sH2[mt * 4 + r] += h * h;
                            sR[mt * 4 + r]  += rv;
                            sR2[mt * 4 + r] += rv * rv;
                        }
                    }
                }
        } else {
#pragma unroll
            for (int mt = 0; mt < 2; ++mt)
#pragma unroll
                for (int nt = 0; nt < 4; ++nt) {
                    int col = nt * 16 + l15;
                    int v = col & 31;
                    int t = t0 + (col >> 5);
                    if (v < V_) {
#pragma unroll
                        for (int r = 0; r < 4; ++r) {
                            int o = wv * 32 + mt * 16 + lq * 4 + r;
                            out[((size_t)(n * COUT + o) * T_ + t) * V_ + v] =
                                scH[mt][r] * accH[mt][nt][r] + scR[mt][r] * accR[mt][nt][r] + bC[mt][r];
                        }
                    }
                }
        }
        __syncthreads();  // before next tile's staging overwrites LDS
    }

    if (PASS == 0) {
#pragma unroll
        for (int i = 0; i < 8; ++i) {
#pragma unroll
            for (int s = 1; s < 16; s <<= 1) {
                sH[i]  += __shfl_xor(sH[i], s);
                sH2[i] += __shfl_xor(sH2[i], s);
                sR[i]  += __shfl_xor(sR[i], s);
                sR2[i] += __shfl_xor(sR2[i], s);
            }
        }
        if (l15 == 0) {
#pragma unroll
            for (int mt = 0; mt < 2; ++mt)
#pragma unroll
                for (int r = 0; r < 4; ++r) {
                    int i = mt * 4 + r;
                    int o = wv * 32 + mt * 16 + lq * 4 + r;
                    atomicAdd(&st[o], sH[i]);
                    atomicAdd(&st[128 + o], sH2[i]);
                    atomicAdd(&st[256 + o], sR[i]);
                    atomicAdd(&st[384 + o], sR2[i]);
                }
        }
    }
}

extern "C" void kernel_launch(void* const* d_in, const int* in_sizes, int n_in,
                              void* d_out, int out_size, void* d_ws, size_t ws_size,
                              hipStream_t stream) {
    const float* x        = (const float*)d_in[0];
    const float* A        = (const float*)d_in[1];
    const float* ga       = (const float*)d_in[2];
    const float* Wg       = (const float*)d_in[3];
    const float* bg       = (const float*)d_in[4];
    const float* bn_gamma = (const float*)d_in[5];
    const float* bn_beta  = (const float*)d_in[6];
    const float* Wr       = (const float*)d_in[7];
    const float* br       = (const float*)d_in[8];
    const float* rbn_g    = (const float*)d_in[9];
    const float* rbn_b    = (const float*)d_in[10];
    char* wsb  = (char*)d_ws;
    float* out = (float*)d_out;

    prep_kernel<<<64, 256, 0, stream>>>(A, ga, Wg, Wr, wsb);
    gcn_kernel<0><<<1200, 256, 0, stream>>>(x, bg, br, wsb, out);
    finalize_kernel<<<1, 128, 0, stream>>>(bn_gamma, bn_beta, rbn_g, rbn_b, wsb);
    gcn_kernel<1><<<1200, 256, 0, stream>>>(x, bg, br, wsb, out);
}

// Round 4
// 246.975 us; speedup vs baseline: 3.5949x; 1.0987x over previous
//
#include <hip/hip_runtime.h>

typedef __attribute__((ext_vector_type(8))) _Float16 half8;
typedef __attribute__((ext_vector_type(4))) float float4v;
typedef float float4u __attribute__((ext_vector_type(4), aligned(4)));
typedef float float2u __attribute__((ext_vector_type(2), aligned(4)));

#define NB   32
#define CIN  64
#define COUT 128
#define TT   300
#define VV   25
#define EPS  1e-5f
#define M_TOT 240000.0f

// ws byte offsets
#define WS_WF    0         // half [8 mt][8 kt][64 l][8 j] = 65536 B (unscaled, pass0)
#define WS_AEF   65536     // half [4 k][2 nt][64 l][8 j]  = 8192 B (k=3 is identity)
#define WS_ST    73728     // float[512]: sH,sH2,sR,sR2 x 128
#define WS_CF    75776     // float[384]: scH, scR, bC
#define WS_WF2   77312     // half [8][8][64][8] = 65536 B (scaled, pass1)

__device__ __forceinline__ unsigned short f2h(float f) {
    return __builtin_bit_cast(unsigned short, (_Float16)f);
}

__device__ __forceinline__ float4v mfma16(half8 a, half8 b, float4v c) {
    return __builtin_amdgcn_mfma_f32_16x16x32_f16(a, b, c, 0, 0, 0);
}

__global__ void prep_kernel(const float* __restrict__ A, const float* __restrict__ ga,
                            const float* __restrict__ Wg, const float* __restrict__ Wr,
                            char* __restrict__ wsb) {
    unsigned short* wf = (unsigned short*)(wsb + WS_WF);
    unsigned short* ae = (unsigned short*)(wsb + WS_AEF);
    float* st = (float*)(wsb + WS_ST);
    int i = blockIdx.x * blockDim.x + threadIdx.x;
    for (; i < 32768 + 4096 + 512; i += gridDim.x * blockDim.x) {
        if (i < 32768) {
            int mt = i >> 12, kt = (i >> 9) & 7, l = (i >> 3) & 63, j = i & 7;
            int o = mt * 16 + (l & 15);
            int kc = kt * 32 + ((l >> 4) << 3) + j;
            float v = (kc < 192) ? Wg[((kc >> 6) * COUT + o) * CIN + (kc & 63)]
                                 : Wr[o * CIN + (kc - 192)];
            wf[i] = f2h(v);
        } else if (i < 32768 + 4096) {
            int q = i - 32768;
            int k = q >> 10, nt = (q >> 9) & 1, l = (q >> 3) & 63, j = q & 7;
            int v = ((l >> 4) << 3) + j, w = nt * 16 + (l & 15);
            float val = 0.0f;
            if (v < VV && w < VV)
                val = (k < 3) ? A[(k * VV + v) * VV + w] * ga[(k * VV + v) * VV + w]
                              : (v == w ? 1.0f : 0.0f);
            ae[q] = f2h(val);
        } else {
            st[i - 36864] = 0.0f;
        }
    }
}

// After pass0: every block recomputes BN coefs from stats, scales weights into WF2.
// Block 0 also publishes cf[] for pass1's fused bias.
__global__ __launch_bounds__(256) void scale_kernel(
        const float* __restrict__ Wg, const float* __restrict__ Wr,
        const float* __restrict__ g1, const float* __restrict__ b1,
        const float* __restrict__ g2, const float* __restrict__ b2,
        char* __restrict__ wsb) {
    const float* st = (const float*)(wsb + WS_ST);
    float* cf = (float*)(wsb + WS_CF);
    unsigned short* wf2 = (unsigned short*)(wsb + WS_WF2);
    __shared__ float cl[384];
    int tid = threadIdx.x;
    if (tid < 128) {
        int o = tid;
        const float inv_m = 1.0f / M_TOT;
        float mH = st[o] * inv_m,        vH = st[128 + o] * inv_m - mH * mH;
        float mR = st[256 + o] * inv_m,  vR = st[384 + o] * inv_m - mR * mR;
        float scH = g1[o] * rsqrtf(vH + EPS);
        float scR = g2[o] * rsqrtf(vR + EPS);
        float bC  = b1[o] + b2[o] - scH * mH - scR * mR;  // conv biases cancel through BN
        cl[o] = scH; cl[128 + o] = scR; cl[256 + o] = bC;
        if (blockIdx.x == 0) { cf[o] = scH; cf[128 + o] = scR; cf[256 + o] = bC; }
    }
    __syncthreads();
    for (int i = blockIdx.x * 256 + tid; i < 32768; i += gridDim.x * 256) {
        int mt = i >> 12, kt = (i >> 9) & 7, l = (i >> 3) & 63, j = i & 7;
        int o = mt * 16 + (l & 15);
        int kc = kt * 32 + ((l >> 4) << 3) + j;
        float v = (kc < 192) ? Wg[((kc >> 6) * COUT + o) * CIN + (kc & 63)] * cl[o]
                             : Wr[o * CIN + (kc - 192)] * cl[128 + o];
        wf2[i] = f2h(v);
    }
}

// PASS 0: raw stats (zero-init acc; pads contribute exact 0). PASS 1: scaled weights + fused bias.
// Block: 256 thr (4 waves); tile = (n, 2 t's) = 64 padded cols; wave wv owns o in [wv*32, wv*32+32).
template <int PASS>
__global__ __launch_bounds__(256, 2) void gcn_kernel(
        const float* __restrict__ x, char* __restrict__ wsb, float* __restrict__ out) {
    __shared__ __align__(16) _Float16 xa[64 * 256];   // [col][kc], XOR-swizzled, 32 KB
    __shared__ __align__(16) _Float16 xs[2][64][40];  // [t][c][v-pad], 80 B rows
    char* xab = (char*)xa;

    const unsigned short* wf = (const unsigned short*)(wsb + (PASS == 0 ? WS_WF : WS_WF2));
    const unsigned short* ae = (const unsigned short*)(wsb + WS_AEF);
    float* st = (float*)(wsb + WS_ST);
    const float* cf = (const float*)(wsb + WS_CF);

    const int tid = threadIdx.x, wv = tid >> 6, l = tid & 63;
    const int l15 = l & 15, lq = l >> 4;

    half8 af[2][8];
#pragma unroll
    for (int mt = 0; mt < 2; ++mt)
#pragma unroll
        for (int kt = 0; kt < 8; ++kt)
            af[mt][kt] = *(const half8*)&wf[(((wv * 2 + mt) * 8 + kt) * 64 + l) * 8];

    half8 aef[4][2];
#pragma unroll
    for (int k = 0; k < 4; ++k)
#pragma unroll
        for (int nt = 0; nt < 2; ++nt)
            aef[k][nt] = *(const half8*)&ae[((k * 2 + nt) * 64 + l) * 8];

    float bC[2][4];
    if (PASS == 1) {
#pragma unroll
        for (int mt = 0; mt < 2; ++mt)
#pragma unroll
            for (int r = 0; r < 4; ++r)
                bC[mt][r] = cf[256 + wv * 32 + mt * 16 + lq * 4 + r];
    }

    float sH[8], sH2[8], sR[8], sR2[8];
    if (PASS == 0) {
#pragma unroll
        for (int i = 0; i < 8; ++i) { sH[i] = 0; sH2[i] = 0; sR[i] = 0; sR2[i] = 0; }
    }

    // zero xs pads (v 25..39) once; staging only ever writes v<25
    for (int e = tid; e < 1920; e += 256) {
        int t = e / 960, r = e % 960;
        xs[t][r / 15][25 + r % 15] = (_Float16)0.0f;
    }

    float4v pre[4];
    auto issue_pre = [&](int n_, int t0_) {
#pragma unroll
        for (int p = 0; p < 4; ++p) {
            int idx = tid + p * 256;
            if (idx < 832) {
                int c = idx / 13, ii = idx - c * 13;
                const float* g = x + n_ * 480000 + c * 7500 + t0_ * 25 + ii * 4;
                if (ii < 12) {
                    float4u v = *(const float4u*)g;
                    pre[p][0] = v[0]; pre[p][1] = v[1]; pre[p][2] = v[2]; pre[p][3] = v[3];
                } else {
                    float2u v = *(const float2u*)g;
                    pre[p][0] = v[0]; pre[p][1] = v[1];
                }
            }
        }
    };
    auto write_xs = [&]() {
#pragma unroll
        for (int p = 0; p < 4; ++p) {
            int idx = tid + p * 256;
            if (idx < 832) {
                int c = idx / 13, ii = idx - c * 13;
#pragma unroll
                for (int s = 0; s < 4; ++s) {
                    int f = ii * 4 + s;
                    if (f < 50) {
                        int tsel = f >= 25;
                        xs[tsel][c][f - tsel * 25] = (_Float16)pre[p][s];
                    }
                }
            }
        }
    };

    const int tile0 = blockIdx.x * 3;
    { int n0 = tile0 / 150, t00 = (tile0 % 150) * 2; issue_pre(n0, t00); }
    write_xs();

    float4v acc[2][4], accH[2][4], accR[2][4];

    for (int it = 0; it < 3; ++it) {
        const int tile = tile0 + it;
        const int n = tile / 150, t0 = (tile % 150) * 2;
        __syncthreads();  // xs ready; xa free

        // ---- stage1: xa[col][kc] = (X . Ae_k)  (k=3 identity -> raw X) ----
#pragma unroll
        for (int t = 0; t < 2; ++t) {
            half8 xf = *(const half8*)&xs[t][wv * 16 + l15][lq * 8];
#pragma unroll
            for (int k = 0; k < 4; ++k)
#pragma unroll
                for (int nt = 0; nt < 2; ++nt) {
                    float4v c4 = {0.0f, 0.0f, 0.0f, 0.0f};
                    c4 = mfma16(xf, aef[k][nt], c4);
                    int col = t * 32 + nt * 16 + l15;
                    int kcb = (k * 64 + wv * 16 + lq * 4) * 2;
                    unsigned p0 = __builtin_bit_cast(unsigned, __builtin_amdgcn_cvt_pkrtz(c4[0], c4[1]));
                    unsigned p1 = __builtin_bit_cast(unsigned, __builtin_amdgcn_cvt_pkrtz(c4[2], c4[3]));
                    unsigned long long pk = ((unsigned long long)p1 << 32) | p0;
                    *(unsigned long long*)(xab + ((col << 9) + (kcb ^ ((col & 7) << 4)))) = pk;
                }
        }
        __syncthreads();  // xa ready; xs free

        const bool hn = (it < 2);
        if (hn) { int tl = tile + 1; issue_pre(tl / 150, (tl % 150) * 2); }

        if (PASS == 0) {
#pragma unroll
            for (int mt = 0; mt < 2; ++mt)
#pragma unroll
                for (int nt = 0; nt < 4; ++nt) {
                    accH[mt][nt] = {0.0f, 0.0f, 0.0f, 0.0f};
                    accR[mt][nt] = {0.0f, 0.0f, 0.0f, 0.0f};
                }
        } else {
#pragma unroll
            for (int mt = 0; mt < 2; ++mt)
#pragma unroll
                for (int nt = 0; nt < 4; ++nt)
#pragma unroll
                    for (int r = 0; r < 4; ++r) acc[mt][nt][r] = bC[mt][r];
        }

        // ---- stage2: K=256 MFMA chain ----
#pragma unroll
        for (int kt = 0; kt < 8; ++kt)
#pragma unroll
            for (int nt = 0; nt < 4; ++nt) {
                int col = nt * 16 + l15;
                half8 bf = *(const half8*)(xab + ((col << 9) +
                               ((kt * 64 + lq * 16) ^ ((col & 7) << 4))));
                if (PASS == 0) {
                    if (kt < 6) {
                        accH[0][nt] = mfma16(af[0][kt], bf, accH[0][nt]);
                        accH[1][nt] = mfma16(af[1][kt], bf, accH[1][nt]);
                    } else {
                        accR[0][nt] = mfma16(af[0][kt], bf, accR[0][nt]);
                        accR[1][nt] = mfma16(af[1][kt], bf, accR[1][nt]);
                    }
                } else {
                    acc[0][nt] = mfma16(af[0][kt], bf, acc[0][nt]);
                    acc[1][nt] = mfma16(af[1][kt], bf, acc[1][nt]);
                }
            }

        // ---- epilogue ----
        if (PASS == 0) {
#pragma unroll
            for (int mt = 0; mt < 2; ++mt)
#pragma unroll
                for (int nt = 0; nt < 4; ++nt)
#pragma unroll
                    for (int r = 0; r < 4; ++r) {
                        float h = accH[mt][nt][r], rv = accR[mt][nt][r];
                        sH[mt * 4 + r] += h;   sH2[mt * 4 + r] += h * h;
                        sR[mt * 4 + r] += rv;  sR2[mt * 4 + r] += rv * rv;
                    }
        } else {
#pragma unroll
            for (int mt = 0; mt < 2; ++mt)
#pragma unroll
                for (int nt = 0; nt < 4; ++nt) {
                    int col = nt * 16 + l15, v = col & 31;
                    if (v < VV) {
                        int t = t0 + (col >> 5);
                        float* op = out + ((size_t)((n * COUT + wv * 32 + mt * 16 + lq * 4)) * TT + t) * VV + v;
                        op[0]     = acc[mt][nt][0];
                        op[7500]  = acc[mt][nt][1];
                        op[15000] = acc[mt][nt][2];
                        op[22500] = acc[mt][nt][3];
                    }
                }
        }

        if (hn) write_xs();
    }

    if (PASS == 0) {
#pragma unroll
        for (int i = 0; i < 8; ++i) {
#pragma unroll
            for (int s = 1; s < 16; s <<= 1) {
                sH[i]  += __shfl_xor(sH[i], s);
                sH2[i] += __shfl_xor(sH2[i], s);
                sR[i]  += __shfl_xor(sR[i], s);
                sR2[i] += __shfl_xor(sR2[i], s);
            }
        }
        if (l15 == 0) {
#pragma unroll
            for (int mt = 0; mt < 2; ++mt)
#pragma unroll
                for (int r = 0; r < 4; ++r) {
                    int i = mt * 4 + r;
                    int o = wv * 32 + mt * 16 + lq * 4 + r;
                    atomicAdd(&st[o], sH[i]);
                    atomicAdd(&st[128 + o], sH2[i]);
                    atomicAdd(&st[256 + o], sR[i]);
                    atomicAdd(&st[384 + o], sR2[i]);
                }
        }
    }
}

extern "C" void kernel_launch(void* const* d_in, const int* in_sizes, int n_in,
                              void* d_out, int out_size, void* d_ws, size_t ws_size,
                              hipStream_t stream) {
    const float* x        = (const float*)d_in[0];
    const float* A        = (const float*)d_in[1];
    const float* ga       = (const float*)d_in[2];
    const float* Wg       = (const float*)d_in[3];
    const float* bn_gamma = (const float*)d_in[5];
    const float* bn_beta  = (const float*)d_in[6];
    const float* Wr       = (const float*)d_in[7];
    const float* rbn_g    = (const float*)d_in[9];
    const float* rbn_b    = (const float*)d_in[10];
    char* wsb  = (char*)d_ws;
    float* out = (float*)d_out;

    prep_kernel<<<64, 256, 0, stream>>>(A, ga, Wg, Wr, wsb);
    gcn_kernel<0><<<1600, 256, 0, stream>>>(x, wsb, nullptr);
    scale_kernel<<<64, 256, 0, stream>>>(Wg, Wr, bn_gamma, bn_beta, rbn_g, rbn_b, wsb);
    gcn_kernel<1><<<1600, 256, 0, stream>>>(x, wsb, out);
}